// Round 2
// baseline (26097.137 us; speedup 1.0000x reference)
//
#include <hip/hip_runtime.h>

#define BATCH 128
#define SEQ   512
#define EMB   512
#define HID   1024
#define KC    1536   // EMB + HID
#define NCLS  1000
#define NBLK  256    // scan grid = CU count (co-resident)

using short8 = __attribute__((ext_vector_type(8))) short;
using f32x4  = __attribute__((ext_vector_type(4))) float;

__device__ __forceinline__ short f2bf(float f) {
    unsigned u = __float_as_uint(f);
    unsigned r = (u + 0x7fffu + ((u >> 16) & 1u)) >> 16;   // RNE
    return (short)r;
}
__device__ __forceinline__ float bf2f(short s) {
    unsigned u = ((unsigned)(unsigned short)s) << 16;
    return __uint_as_float(u);
}

// ---------------- init: build c0/l0 (t=0 A-matrix, bf16 hi+lo), zero h, reset barrier ----
__global__ void mgu_init(const int* __restrict__ x, const float* __restrict__ emb,
                         float* __restrict__ h, short* __restrict__ c0,
                         short* __restrict__ l0, unsigned* __restrict__ bar) {
    int i = blockIdx.x * blockDim.x + threadIdx.x;
    if (i == 0) *bar = 0u;
    if (i < BATCH * KC) {
        int b = i / KC;
        int col = i - b * KC;
        float v = 0.f;
        if (col < EMB) v = emb[(long)x[b * SEQ] * EMB + col];
        c0[i] = f2bf(v);                 // h0 = 0 -> zeros for col >= EMB
    } else {
        int j = i - BATCH * KC;
        if (j < BATCH * HID) { h[j] = 0.f; l0[j] = 0; }
    }
}

// ---------------- global barrier (monotonic counter, agent scope) ----------------
__device__ __forceinline__ void gbar(unsigned* bar, unsigned target) {
    __threadfence();            // order this thread's writes before arrival
    __syncthreads();            // whole block done writing
    if (threadIdx.x == 0) {
        __hip_atomic_fetch_add(bar, 1u, __ATOMIC_RELEASE, __HIP_MEMORY_SCOPE_AGENT);
        while (__hip_atomic_load(bar, __ATOMIC_RELAXED, __HIP_MEMORY_SCOPE_AGENT) < target)
            __builtin_amdgcn_s_sleep(2);
        __threadfence();        // acquire: invalidate stale L1/L2 before reads
    }
    __syncthreads();
}

// ---------------- sequential scan: regular launch + software grid barrier ----------------
// 256 blocks x 256 threads = 1024 waves = 1024 16x16 output tiles of [128,1536+]x[...,2048].
// Wave tile: 16 rows x (8 z-cols + 8 htilde-cols interleaved via lane n<8 / n>=8).
// Weights resident in VGPRs: 48 x short8 = 192 VGPRs/lane, loaded once.
// h kept as fp32 + split-bf16 (hi+lo) A-operand: 32 extra MFMAs reuse Bf[16..47].
__global__ __launch_bounds__(256, 1) void mgu_scan(
    const int* __restrict__ x, const float* __restrict__ emb,
    const float* __restrict__ Wz, const float* __restrict__ bz,
    const float* __restrict__ Wh, const float* __restrict__ bh,
    float* __restrict__ h, short* __restrict__ c0, short* __restrict__ c1,
    short* __restrict__ l0, short* __restrict__ l1, unsigned* __restrict__ bar)
{
    const int tid  = threadIdx.x;
    const int w    = tid >> 6;               // wave in block 0..3
    const int lane = tid & 63;
    const int q    = lane >> 4;              // quad 0..3
    const int n    = lane & 15;              // MFMA col (and A-row) index
    const int blk  = blockIdx.x;
    const int r0   = (blk >> 5) << 4;        // 16-row group base (8 groups)
    const int cgi  = ((blk & 31) << 2) + w;  // col group 0..127
    const int j0   = cgi << 3;               // 8 gate-columns per wave

    // persistent weight fragments: lane n<8 -> Wz cols j0+n ; n>=8 -> Wh cols j0+(n-8)
    // B-frag layout (m89-verified family): B[k = q*8+i][col = lane&15]
    const float* Wg = (n < 8) ? Wz : Wh;
    const float* wp = Wg + j0 + (n & 7);
    short8 Bf[48];
#pragma unroll
    for (int ks = 0; ks < 48; ++ks) {
        short8 f;
#pragma unroll
        for (int i = 0; i < 8; ++i)
            f[i] = f2bf(wp[(long)(ks * 32 + q * 8 + i) * HID]);
        Bf[ks] = f;
    }

    const float bzv = bz[j0 + (n & 7)];
    const float bhv = bh[j0 + (n & 7)];

    for (int t = 0; t < SEQ; ++t) {
        const short* cc = (t & 1) ? c1 : c0;   // current A hi [128][1536]
        short*       cn = (t & 1) ? c0 : c1;
        const short* lc = (t & 1) ? l1 : l0;   // current A lo (h block) [128][1024]
        short*       ln = (t & 1) ? l0 : l1;

        // embedding gather for step t+1 into cn[:, 0:512] (overlaps with MFMA below)
        if (t < SEQ - 1 && cgi < 64) {
            int col   = (cgi << 3) + (lane & 7);
            int rbase = r0 + (lane >> 3);
#pragma unroll
            for (int rr = 0; rr < 2; ++rr) {
                int b   = rbase + rr * 8;
                int tok = x[b * SEQ + t + 1];
                cn[b * KC + col] = f2bf(emb[(long)tok * EMB + col]);
            }
        }

        // A-frag: A[m = lane&15][k = q*8+i] ; row = r0 + n
        const short* ap  = cc + (r0 + n) * KC  + q * 8;
        const short* alp = lc + (r0 + n) * HID + q * 8;
        f32x4 a0 = {0.f,0.f,0.f,0.f}, a1 = a0, a2 = a0, a3 = a0;
#pragma unroll
        for (int ks = 0; ks < 48; ks += 4) {
            short8 f0 = *(const short8*)(ap + (ks + 0) * 32);
            short8 f1 = *(const short8*)(ap + (ks + 1) * 32);
            short8 f2 = *(const short8*)(ap + (ks + 2) * 32);
            short8 f3 = *(const short8*)(ap + (ks + 3) * 32);
            a0 = __builtin_amdgcn_mfma_f32_16x16x32_bf16(f0, Bf[ks + 0], a0, 0, 0, 0);
            a1 = __builtin_amdgcn_mfma_f32_16x16x32_bf16(f1, Bf[ks + 1], a1, 0, 0, 0);
            a2 = __builtin_amdgcn_mfma_f32_16x16x32_bf16(f2, Bf[ks + 2], a2, 0, 0, 0);
            a3 = __builtin_amdgcn_mfma_f32_16x16x32_bf16(f3, Bf[ks + 3], a3, 0, 0, 0);
        }
        // low-order h correction: k in [512,1536) reuses Bf[16..47]
#pragma unroll
        for (int e = 0; e < 32; e += 4) {
            short8 g0 = *(const short8*)(alp + (e + 0) * 32);
            short8 g1 = *(const short8*)(alp + (e + 1) * 32);
            short8 g2 = *(const short8*)(alp + (e + 2) * 32);
            short8 g3 = *(const short8*)(alp + (e + 3) * 32);
            a0 = __builtin_amdgcn_mfma_f32_16x16x32_bf16(g0, Bf[16 + e + 0], a0, 0, 0, 0);
            a1 = __builtin_amdgcn_mfma_f32_16x16x32_bf16(g1, Bf[16 + e + 1], a1, 0, 0, 0);
            a2 = __builtin_amdgcn_mfma_f32_16x16x32_bf16(g2, Bf[16 + e + 2], a2, 0, 0, 0);
            a3 = __builtin_amdgcn_mfma_f32_16x16x32_bf16(g3, Bf[16 + e + 3], a3, 0, 0, 0);
        }
        f32x4 acc = (a0 + a1) + (a2 + a3);

        // lanes n<8: z-pre for col j0+n; lanes n>=8: htilde-pre for same col. Partner = lane^8.
        float o0 = __shfl_xor(acc[0], 8, 64);
        float o1 = __shfl_xor(acc[1], 8, 64);
        float o2 = __shfl_xor(acc[2], 8, 64);
        float o3 = __shfl_xor(acc[3], 8, 64);

        if (n < 8) {
            float zp[4] = {acc[0], acc[1], acc[2], acc[3]};
            float tp[4] = {o0, o1, o2, o3};
            const int j = j0 + n;
            float* hp = h  + (r0 + q * 4) * HID + j;
            short* cp = cn + (r0 + q * 4) * KC  + EMB + j;
            short* lp = ln + (r0 + q * 4) * HID + j;
#pragma unroll
            for (int r2 = 0; r2 < 4; ++r2) {
                float z  = 1.f / (1.f + __expf(-(zp[r2] + bzv)));
                float ht = tanhf(tp[r2] + bhv);
                float ho = hp[r2 * HID];
                float hn = ho + z * (ht - ho);     // (1-z)*h + z*h~
                hp[r2 * HID] = hn;                 // fp32 state
                short hi = f2bf(hn);
                cp[r2 * KC]  = hi;                 // bf16 hi for next GEMM
                lp[r2 * HID] = f2bf(hn - bf2f(hi));// bf16 lo correction
            }
        }

        if (t < SEQ - 1) gbar(bar, (unsigned)(t + 1) * NBLK);
    }
}

// ---------------- final FC: logits = h @ Wfc + bfc, full fp32 ----------------
__global__ __launch_bounds__(256) void mgu_fc(const float* __restrict__ h,
                                              const float* __restrict__ Wfc,
                                              const float* __restrict__ bfc,
                                              float* __restrict__ out) {
    __shared__ float hs[BATCH][65];       // +1 pad: conflict-free
    const int tid = threadIdx.x;
    const int n0  = blockIdx.x * 8;
    const int b   = tid & 127;
    const int nn  = tid >> 7;             // 0..1
    const int nc  = n0 + nn * 4;
    float acc0 = 0.f, acc1 = 0.f, acc2 = 0.f, acc3 = 0.f;

    for (int k0 = 0; k0 < HID; k0 += 64) {
        __syncthreads();
#pragma unroll
        for (int jj = 0; jj < 8; ++jj) {
            int idx = tid + jj * 256;         // 0..2047
            int bb  = idx >> 4;
            int kk  = (idx & 15) << 2;
            const float4 v = *(const float4*)(h + bb * HID + k0 + kk);
            hs[bb][kk] = v.x; hs[bb][kk + 1] = v.y; hs[bb][kk + 2] = v.z; hs[bb][kk + 3] = v.w;
        }
        __syncthreads();
#pragma unroll 8
        for (int k = 0; k < 64; ++k) {
            float hv = hs[b][k];
            const float4 wv = *(const float4*)(Wfc + (long)(k0 + k) * NCLS + nc);
            acc0 += hv * wv.x; acc1 += hv * wv.y; acc2 += hv * wv.z; acc3 += hv * wv.w;
        }
    }
    float* op = out + b * NCLS + nc;
    op[0] = acc0 + bfc[nc + 0];
    op[1] = acc1 + bfc[nc + 1];
    op[2] = acc2 + bfc[nc + 2];
    op[3] = acc3 + bfc[nc + 3];
}

extern "C" void kernel_launch(void* const* d_in, const int* in_sizes, int n_in,
                              void* d_out, int out_size, void* d_ws, size_t ws_size,
                              hipStream_t stream) {
    const int*   x   = (const int*)  d_in[0];
    const float* emb = (const float*)d_in[1];
    const float* Wz  = (const float*)d_in[2];
    const float* bz  = (const float*)d_in[3];
    const float* Wh  = (const float*)d_in[4];
    const float* bh  = (const float*)d_in[5];
    const float* Wfc = (const float*)d_in[6];
    const float* bfc = (const float*)d_in[7];
    float* out = (float*)d_out;

    char* ws = (char*)d_ws;
    float*    h   = (float*)   ws;                       // 512 KB
    short*    c0  = (short*)  (ws + (512u  << 10));      // 384 KB
    short*    c1  = (short*)  (ws + (896u  << 10));      // 384 KB
    short*    l0  = (short*)  (ws + (1280u << 10));      // 256 KB
    short*    l1  = (short*)  (ws + (1536u << 10));      // 256 KB
    unsigned* bar = (unsigned*)(ws + (1792u << 10));     // 4 B

    // init c0/l0 + zero h + reset barrier
    mgu_init<<<1280, 256, 0, stream>>>(x, emb, h, c0, l0, bar);

    // sequential scan: regular launch, software grid barrier (grid == CU count)
    mgu_scan<<<NBLK, 256, 0, stream>>>(x, emb, Wz, bz, Wh, bh, h, c0, c1, l0, l1, bar);

    // final classifier
    mgu_fc<<<125, 256, 0, stream>>>(h, Wfc, bfc, out);
}

// Round 3
// 3511.827 us; speedup vs baseline: 7.4312x; 7.4312x over previous
//
#include <hip/hip_runtime.h>

#define BATCH 128
#define SEQ   512
#define EMB   512
#define HID   1024
#define KC    1536   // EMB + HID
#define NCLS  1000
#define NBLK  128    // 8 row groups x 16 blocks
#define TPB   512    // 8 waves = 8 col groups per block

using short8 = __attribute__((ext_vector_type(8))) short;
using f32x4  = __attribute__((ext_vector_type(4))) float;
typedef unsigned long long u64;

__device__ __forceinline__ short f2bf(float f) {
    unsigned u = __float_as_uint(f);
    unsigned r = (u + 0x7fffu + ((u >> 16) & 1u)) >> 16;   // RNE
    return (short)r;
}
__device__ __forceinline__ float bf2f(short s) {
    unsigned u = ((unsigned)(unsigned short)s) << 16;
    return __uint_as_float(u);
}

// ---- ws layout (bytes) ----
// ch0/cl0 are the t=0 read buffers (must be zero); bars follow; then ch1/cl1/h.
#define OFF_CH0 0u
#define OFF_CL0 262144u
#define OFF_BAR 524288u          // 8 counters, 256B apart
#define OFF_CH1 526336u
#define OFF_CL1 788480u
#define OFF_H   1050624u
#define ZERO_I4 32896u           // first 526336 bytes zeroed as int4

__global__ void mgu_init(int4* __restrict__ ws4) {
    unsigned i = blockIdx.x * blockDim.x + threadIdx.x;
    if (i < ZERO_I4) ws4[i] = make_int4(0, 0, 0, 0);
}

// ---------------- sequential scan ----------------
// 128 blocks x 512 threads. Block b: row group r0 = (b>>4)*16 (16 batch rows),
// wave w covers gate-cols j0 = ((b&15)*8+w)*8 .. +7 (z in lanes n<8, h~ in n>=8).
// Weights resident in VGPRs (48 x short8 = 192 VGPRs/lane). h state in registers.
// Cross-block exchange: bf16 hi+lo h arrays via relaxed AGENT-scope atomics
// (bypass non-coherent L1/L2, coherence point = LLC) -> NO fences, NO L2 writeback.
// Row groups are fully independent: 8 separate 16-block barriers.
__global__ __launch_bounds__(TPB, 1) void mgu_scan(
    const int* __restrict__ x, const float* __restrict__ emb,
    const float* __restrict__ Wz, const float* __restrict__ bz,
    const float* __restrict__ Wh, const float* __restrict__ bh,
    short* __restrict__ ch0, short* __restrict__ cl0,
    short* __restrict__ ch1, short* __restrict__ cl1,
    unsigned* __restrict__ bars, float* __restrict__ h)
{
    __shared__ short As[16][1544];   // [row][k]: k<512 emb bf16, k>=512 h hi (pad->2-way free)
    __shared__ short Al[16][1032];   // [row][hcol]: h lo correction

    const int tid  = threadIdx.x;
    const int w    = tid >> 6;               // wave 0..7
    const int lane = tid & 63;
    const int q    = lane >> 4;              // quad 0..3
    const int n    = lane & 15;              // MFMA col / A-row index
    const int blk  = blockIdx.x;
    const int r0   = (blk >> 4) << 4;        // row-group base
    const int j0   = (((blk & 15) << 3) + w) << 3;
    unsigned* bar  = bars + ((blk >> 4) << 6);   // 256B-spaced counter per row group

    // ---- persistent weight fragments (B-frag: B[k=q*8+i][col=lane&15]) ----
    const float* Wg = (n < 8) ? Wz : Wh;
    const float* wp = Wg + j0 + (n & 7);
    short8 Bf[48];
#pragma unroll
    for (int ks = 0; ks < 48; ++ks) {
        short8 f;
#pragma unroll
        for (int i = 0; i < 8; ++i)
            f[i] = f2bf(wp[(long)(ks * 32 + q * 8 + i) * HID]);
        Bf[ks] = f;
    }
    const float bzv = bz[j0 + (n & 7)];
    const float bhv = bh[j0 + (n & 7)];

    float hreg[4] = {0.f, 0.f, 0.f, 0.f};    // lanes n<8: h state, rows r0+q*4+r2, col j0+n

    const int hrow = tid >> 5;               // emb staging: 16 rows x 32 threads
    const int hc0  = (tid & 31) << 4;        // 16 cols per thread

    auto stage_emb = [&](int tt) {           // gather emb[x[row,tt]] -> As[:,0:512] (cached loads ok: read-only)
        int tok = x[(r0 + hrow) * SEQ + tt];
        const float4* ep = (const float4*)(emb + (long)tok * EMB + hc0);
        float4 e0 = ep[0], e1 = ep[1], e2 = ep[2], e3 = ep[3];
        short8 s0, s1;
        s0[0] = f2bf(e0.x); s0[1] = f2bf(e0.y); s0[2] = f2bf(e0.z); s0[3] = f2bf(e0.w);
        s0[4] = f2bf(e1.x); s0[5] = f2bf(e1.y); s0[6] = f2bf(e1.z); s0[7] = f2bf(e1.w);
        s1[0] = f2bf(e2.x); s1[1] = f2bf(e2.y); s1[2] = f2bf(e2.z); s1[3] = f2bf(e2.w);
        s1[4] = f2bf(e3.x); s1[5] = f2bf(e3.y); s1[6] = f2bf(e3.z); s1[7] = f2bf(e3.w);
        *(short8*)&As[hrow][hc0]     = s0;
        *(short8*)&As[hrow][hc0 + 8] = s1;
    };

    stage_emb(0);

    for (int t = 0; t < SEQ; ++t) {
        const short* chR = (t & 1) ? ch1 : ch0;
        const short* clR = (t & 1) ? cl1 : cl0;
        short*       chW = (t & 1) ? ch0 : ch1;
        short*       clW = (t & 1) ? cl0 : cl1;

        // ---- stage h hi/lo -> LDS (coherent agent loads, 8B each; 16/thread) ----
        u64 hv[8], lv[8];
#pragma unroll
        for (int k2 = 0; k2 < 8; ++k2) {
            int idx = tid + (k2 << 9);
            int row = idx >> 8;
            int wc  = idx & 255;
            const u64* hp8 = (const u64*)(chR + (r0 + row) * HID);
            const u64* lp8 = (const u64*)(clR + (r0 + row) * HID);
            hv[k2] = __hip_atomic_load(hp8 + wc, __ATOMIC_RELAXED, __HIP_MEMORY_SCOPE_AGENT);
            lv[k2] = __hip_atomic_load(lp8 + wc, __ATOMIC_RELAXED, __HIP_MEMORY_SCOPE_AGENT);
        }
#pragma unroll
        for (int k2 = 0; k2 < 8; ++k2) {
            int idx = tid + (k2 << 9);
            int row = idx >> 8;
            int wc  = idx & 255;
            *(u64*)&As[row][512 + (wc << 2)] = hv[k2];
            *(u64*)&Al[row][wc << 2]         = lv[k2];
        }
        __syncthreads();

        // ---- MFMA: A from LDS, B resident ----
        const short* ap  = &As[n][q * 8];
        const short* alp = &Al[n][q * 8];
        f32x4 a0 = {0.f,0.f,0.f,0.f}, a1 = a0, a2 = a0, a3 = a0;
#pragma unroll
        for (int ks = 0; ks < 48; ks += 4) {
            short8 f0 = *(const short8*)(ap + (ks + 0) * 32);
            short8 f1 = *(const short8*)(ap + (ks + 1) * 32);
            short8 f2 = *(const short8*)(ap + (ks + 2) * 32);
            short8 f3 = *(const short8*)(ap + (ks + 3) * 32);
            a0 = __builtin_amdgcn_mfma_f32_16x16x32_bf16(f0, Bf[ks + 0], a0, 0, 0, 0);
            a1 = __builtin_amdgcn_mfma_f32_16x16x32_bf16(f1, Bf[ks + 1], a1, 0, 0, 0);
            a2 = __builtin_amdgcn_mfma_f32_16x16x32_bf16(f2, Bf[ks + 2], a2, 0, 0, 0);
            a3 = __builtin_amdgcn_mfma_f32_16x16x32_bf16(f3, Bf[ks + 3], a3, 0, 0, 0);
        }
#pragma unroll
        for (int e = 0; e < 32; e += 4) {    // lo correction reuses Bf[16..47]
            short8 g0 = *(const short8*)(alp + (e + 0) * 32);
            short8 g1 = *(const short8*)(alp + (e + 1) * 32);
            short8 g2 = *(const short8*)(alp + (e + 2) * 32);
            short8 g3 = *(const short8*)(alp + (e + 3) * 32);
            a0 = __builtin_amdgcn_mfma_f32_16x16x32_bf16(g0, Bf[16 + e + 0], a0, 0, 0, 0);
            a1 = __builtin_amdgcn_mfma_f32_16x16x32_bf16(g1, Bf[16 + e + 1], a1, 0, 0, 0);
            a2 = __builtin_amdgcn_mfma_f32_16x16x32_bf16(g2, Bf[16 + e + 2], a2, 0, 0, 0);
            a3 = __builtin_amdgcn_mfma_f32_16x16x32_bf16(g3, Bf[16 + e + 3], a3, 0, 0, 0);
        }
        f32x4 acc = (a0 + a1) + (a2 + a3);

        // z-pre in lanes n<8, h~-pre in lanes n>=8 (same col); partner = lane^8
        float o0 = __shfl_xor(acc[0], 8, 64);
        float o1 = __shfl_xor(acc[1], 8, 64);
        float o2 = __shfl_xor(acc[2], 8, 64);
        float o3 = __shfl_xor(acc[3], 8, 64);

        if (n < 8) {
            float zp[4] = {acc[0], acc[1], acc[2], acc[3]};
            float tp[4] = {o0, o1, o2, o3};
            const int j = j0 + n;
#pragma unroll
            for (int r2 = 0; r2 < 4; ++r2) {
                float z  = 1.f / (1.f + __expf(-(zp[r2] + bzv)));
                float ht = tanhf(tp[r2] + bhv);
                float ho = hreg[r2];
                float hn = ho + z * (ht - ho);
                hreg[r2] = hn;
                int rr = (r0 + q * 4 + r2) * HID + j;
                if (t < SEQ - 1) {
                    short hi = f2bf(hn);
                    __hip_atomic_store(chW + rr, hi, __ATOMIC_RELAXED, __HIP_MEMORY_SCOPE_AGENT);
                    __hip_atomic_store(clW + rr, f2bf(hn - bf2f(hi)), __ATOMIC_RELAXED, __HIP_MEMORY_SCOPE_AGENT);
                } else {
                    h[rr] = hn;          // final state, normal store (kernel-boundary flush)
                }
            }
        }

        if (t < SEQ - 1) {
            // release: __syncthreads drains vmcnt(0) (bypass stores complete => visible at LLC)
            __syncthreads();
            if (tid == 0)
                __hip_atomic_fetch_add(bar, 1u, __ATOMIC_RELAXED, __HIP_MEMORY_SCOPE_AGENT);
            stage_emb(t + 1);            // overlap emb gather with barrier wait
            if (tid == 0) {
                unsigned tgt = (unsigned)(t + 1) * 16u;
                while (__hip_atomic_load(bar, __ATOMIC_RELAXED, __HIP_MEMORY_SCOPE_AGENT) < tgt)
                    __builtin_amdgcn_s_sleep(1);
            }
            __syncthreads();
        }
    }
}

// ---------------- final FC: logits = h @ Wfc + bfc, full fp32 ----------------
__global__ __launch_bounds__(256) void mgu_fc(const float* __restrict__ h,
                                              const float* __restrict__ Wfc,
                                              const float* __restrict__ bfc,
                                              float* __restrict__ out) {
    __shared__ float hs[BATCH][65];
    const int tid = threadIdx.x;
    const int n0  = blockIdx.x * 8;
    const int b   = tid & 127;
    const int nn  = tid >> 7;
    const int nc  = n0 + nn * 4;
    float acc0 = 0.f, acc1 = 0.f, acc2 = 0.f, acc3 = 0.f;

    for (int k0 = 0; k0 < HID; k0 += 64) {
        __syncthreads();
#pragma unroll
        for (int jj = 0; jj < 8; ++jj) {
            int idx = tid + jj * 256;
            int bb  = idx >> 4;
            int kk  = (idx & 15) << 2;
            const float4 v = *(const float4*)(h + bb * HID + k0 + kk);
            hs[bb][kk] = v.x; hs[bb][kk + 1] = v.y; hs[bb][kk + 2] = v.z; hs[bb][kk + 3] = v.w;
        }
        __syncthreads();
#pragma unroll 8
        for (int k = 0; k < 64; ++k) {
            float hv = hs[b][k];
            const float4 wv = *(const float4*)(Wfc + (long)(k0 + k) * NCLS + nc);
            acc0 += hv * wv.x; acc1 += hv * wv.y; acc2 += hv * wv.z; acc3 += hv * wv.w;
        }
    }
    float* op = out + b * NCLS + nc;
    op[0] = acc0 + bfc[nc + 0];
    op[1] = acc1 + bfc[nc + 1];
    op[2] = acc2 + bfc[nc + 2];
    op[3] = acc3 + bfc[nc + 3];
}

extern "C" void kernel_launch(void* const* d_in, const int* in_sizes, int n_in,
                              void* d_out, int out_size, void* d_ws, size_t ws_size,
                              hipStream_t stream) {
    const int*   x   = (const int*)  d_in[0];
    const float* emb = (const float*)d_in[1];
    const float* Wz  = (const float*)d_in[2];
    const float* bz  = (const float*)d_in[3];
    const float* Wh  = (const float*)d_in[4];
    const float* bh  = (const float*)d_in[5];
    const float* Wfc = (const float*)d_in[6];
    const float* bfc = (const float*)d_in[7];
    float* out = (float*)d_out;

    char* ws = (char*)d_ws;
    short*    ch0  = (short*)   (ws + OFF_CH0);
    short*    cl0  = (short*)   (ws + OFF_CL0);
    unsigned* bars = (unsigned*)(ws + OFF_BAR);
    short*    ch1  = (short*)   (ws + OFF_CH1);
    short*    cl1  = (short*)   (ws + OFF_CL1);
    float*    h    = (float*)   (ws + OFF_H);

    mgu_init<<<129, 256, 0, stream>>>((int4*)ws);   // zero ch0/cl0/bars

    mgu_scan<<<NBLK, TPB, 0, stream>>>(x, emb, Wz, bz, Wh, bh,
                                       ch0, cl0, ch1, cl1, bars, h);

    mgu_fc<<<125, 256, 0, stream>>>(h, Wfc, bfc, out);
}